// Round 7
// baseline (10399.198 us; speedup 1.0000x reference)
//
#include <hip/hip_runtime.h>

// CV quantum neural network simulator, D=8 cutoff, M=4 modes, L=4 layers.
// R7 = R6 with corrected staging sizes: BS table = 512 float2 = 256 float4
// (ALL 256 threads stage one float4), single-mode table = 64 float2 = 32
// float4. R6 staged half -> waves 2,3 read uninitialized LDS -> NaN.
// Gate tables: global -> float4/thread -> 4KB LDS buffer (stored in write
// phase behind the mid-barrier); inner loops read G via LDS broadcast.

#define NM 4
#define NL 4
#define AMPS 4096

__device__ __forceinline__ void cmac(float2& acc, float2 a, float2 b) {
    acc.x = fmaf(a.x, b.x, acc.x);
    acc.x = fmaf(-a.y, b.y, acc.x);
    acc.y = fmaf(a.x, b.y, acc.y);
    acc.y = fmaf(a.y, b.x, acc.y);
}
__device__ __forceinline__ float2 cmul(float2 a, float2 b) {
    return make_float2(a.x * b.x - a.y * b.y, a.x * b.y + a.y * b.x);
}

// F2-linear physical-slot map (bank-conflict-free for all access patterns).
// XOR-linear: physw(a^b) = physw(a)^physw(b).
__device__ __host__ __forceinline__ constexpr int physw(int e) {
    int l0 = ((e >> 0) ^ (e >> 5) ^ (e >> 7) ^ (e >> 9)) & 1;
    int l1 = ((e >> 1) ^ (e >> 3) ^ (e >> 8) ^ (e >> 10)) & 1;
    int l2 = ((e >> 2) ^ (e >> 4) ^ (e >> 6) ^ (e >> 11)) & 1;
    int l3 = ((e >> 3) ^ (e >> 6) ^ (e >> 9)) & 1;
    return (e & ~15) | l0 | (l1 << 1) | (l2 << 2) | (l3 << 3);
}

// ---------------------------------------------------------------------------
// Kernel 1: coherent vectors = first column of expm(x*(AD - A)).
// ---------------------------------------------------------------------------
__global__ void coh_kernel(const float* __restrict__ x, float* __restrict__ coh, int total) {
    int t = blockIdx.x * blockDim.x + threadIdx.x;
    if (t >= total) return;
    float alpha = x[t];
    const float sq1 = 1.0f, sq2 = 1.41421356f, sq3 = 1.73205081f, sq4 = 2.0f,
                sq5 = 2.23606798f, sq6 = 2.44948975f, sq7 = 2.64575131f;
    float v0 = 1.f, v1 = 0.f, v2 = 0.f, v3 = 0.f, v4 = 0.f, v5 = 0.f, v6 = 0.f, v7 = 0.f;
    const int NS = 32;
    float h = alpha / (float)NS;
    for (int s = 0; s < NS; s++) {
        float w0 = v0, w1 = v1, w2 = v2, w3 = v3, w4 = v4, w5 = v5, w6 = v6, w7 = v7;
        float t0 = v0, t1 = v1, t2 = v2, t3 = v3, t4 = v4, t5 = v5, t6 = v6, t7 = v7;
        #pragma unroll
        for (int j = 1; j <= 8; j++) {
            float c = h / (float)j;
            float n0 = c * (          - sq1 * t1);
            float n1 = c * (sq1 * t0 - sq2 * t2);
            float n2 = c * (sq2 * t1 - sq3 * t3);
            float n3 = c * (sq3 * t2 - sq4 * t4);
            float n4 = c * (sq4 * t3 - sq5 * t5);
            float n5 = c * (sq5 * t4 - sq6 * t6);
            float n6 = c * (sq6 * t5 - sq7 * t7);
            float n7 = c * (sq7 * t6            );
            t0 = n0; t1 = n1; t2 = n2; t3 = n3; t4 = n4; t5 = n5; t6 = n6; t7 = n7;
            w0 += t0; w1 += t1; w2 += t2; w3 += t3; w4 += t4; w5 += t5; w6 += t6; w7 += t7;
        }
        v0 = w0; v1 = w1; v2 = w2; v3 = w3; v4 = w4; v5 = w5; v6 = w6; v7 = w7;
    }
    float* dst = coh + t * 8;
    dst[0] = v0; dst[1] = v1; dst[2] = v2; dst[3] = v3;
    dst[4] = v4; dst[5] = v5; dst[6] = v6; dst[7] = v7;
}

// ---------------------------------------------------------------------------
// Kernel 2: 8x8 complex expm. Blocks 0..15: squeeze. Blocks 16..31:
// displacement with Kerr folded (row scale). Stored transposed [k*8+i].
// ---------------------------------------------------------------------------
__global__ __launch_bounds__(64) void expm8_kernel(
    const float* __restrict__ sqr, const float* __restrict__ sqph,
    const float* __restrict__ dpr, const float* __restrict__ dpph,
    const float* __restrict__ kerr,
    float2* __restrict__ sqm, float2* __restrict__ dpm) {
    __shared__ float2 X[64], R[64];
    int t = threadIdx.x;
    int r = t >> 3, c = t & 7;
    int bid = blockIdx.x;
    float2 h = make_float2(0.f, 0.f);
    float normb;
    if (bid < 16) {
        float rr = sqr[bid], ph = sqph[bid];
        float zr = rr * cosf(ph), zi = rr * sinf(ph);
        if (c == r + 2) { float f = 0.5f * sqrtf((float)((r + 1) * (r + 2))); h.x =  f * zr; h.y = -f * zi; }
        if (r == c + 2) { float f = 0.5f * sqrtf((float)((c + 1) * (c + 2))); h.x = -f * zr; h.y = -f * zi; }
        normb = fabsf(rr) * 5.5f;
    } else {
        int g = bid - 16;
        float rr = dpr[g], ph = dpph[g];
        float am = rr * cosf(ph);
        float aph = rr * sinf(ph);
        float ar = am * cosf(aph), ai = am * sinf(aph);
        if (r == c + 1) { float f = sqrtf((float)r); h.x += ar * f; h.y += ai * f; }
        if (c == r + 1) { float f = sqrtf((float)c); h.x -= ar * f; h.y += ai * f; }
        normb = fabsf(am) * 5.5f;
    }
    int s = 0;
    while (normb > 0.2f && s < 20) { normb *= 0.5f; s++; }
    float fs = 1.f;
    for (int q = 0; q < s; q++) fs *= 0.5f;
    float2 xs = make_float2(h.x * fs, h.y * fs);
    X[t] = xs;
    float idel = (r == c) ? 1.f : 0.f;
    R[t] = make_float2(idel + xs.x / 9.f, xs.y / 9.f);
    __syncthreads();
    for (int j = 8; j >= 1; j--) {
        float2 acc = make_float2(0.f, 0.f);
        #pragma unroll
        for (int k = 0; k < 8; k++) cmac(acc, X[r * 8 + k], R[k * 8 + c]);
        __syncthreads();
        float inv = 1.f / (float)j;
        R[t] = make_float2(idel + acc.x * inv, acc.y * inv);
        __syncthreads();
    }
    for (int q = 0; q < s; q++) {
        float2 acc = make_float2(0.f, 0.f);
        #pragma unroll
        for (int k = 0; k < 8; k++) cmac(acc, R[r * 8 + k], R[k * 8 + c]);
        __syncthreads();
        R[t] = acc;
        __syncthreads();
    }
    float2 v = R[t];
    if (bid >= 16) {
        float kp = kerr[bid - 16];
        float ang = kp * (float)(r * r);
        float sn, cs; __sincosf(ang, &sn, &cs);
        v = cmul(make_float2(cs, sn), v);
        dpm[(bid - 16) * 64 + c * 8 + r] = v;
    } else {
        sqm[bid * 64 + c * 8 + r] = v;
    }
}

// ---------------------------------------------------------------------------
// Kernel 3: 64x64 complex expm for 48 beamsplitters, diag rotations folded.
// Output layout: bsG[blk*512 + o*8 + ka] = U'[o][ka*8+kb], kb = n(o)-ka,
// ZERO if kb outside [0,7].  (o = output index 0..63)
// ---------------------------------------------------------------------------
__global__ __launch_bounds__(256) void expm64_kernel(
    const float* __restrict__ th1, const float* __restrict__ ph1,
    const float* __restrict__ th2, const float* __restrict__ ph2,
    float2* __restrict__ bsG) {
    __shared__ float2 X[4096], R[4096];
    int blk = blockIdx.x;
    int l = blk / 12, idx = blk % 12;
    int p = (idx < 6) ? idx : idx - 6;
    int mi = (p < 3) ? 0 : ((p < 5) ? 1 : 2);
    int mj = (p == 0) ? 1 : ((p == 1 || p == 3) ? 2 : 3);
    const float* th = (idx < 6) ? th1 : th2;
    const float* ph = (idx < 6) ? ph1 : ph2;
    float tt = th[l * 16 + mi * 4 + mj];
    float pp = ph[l * 16 + mi * 4 + mj];
    float cp = cosf(pp), sp = sinf(pp);
    float php = ph[l * 16 + mj * 4 + mi];
    float pre_i = 0.f, pre_j = 0.f;
    if (p == 0) { pre_i = ph[l * 16 + 0]; pre_j = ph[l * 16 + 5]; }
    else if (p == 1) { pre_j = ph[l * 16 + 10]; }
    else if (p == 2) { pre_j = ph[l * 16 + 15]; }
    int t = threadIdx.x;
    float normb = fabsf(tt) * 13.94f;
    int s = 0;
    while (normb > 0.2f && s < 20) { normb *= 0.5f; s++; }
    float fs = 1.f;
    for (int q = 0; q < s; q++) fs *= 0.5f;
    for (int e = t; e < 4096; e += 256) {
        int r = e >> 6, c = e & 63;
        int a = r >> 3, b = r & 7, ca = c >> 3, cb = c & 7;
        float2 h = make_float2(0.f, 0.f);
        if (ca == a + 1 && cb == b - 1) {
            float g = tt * sqrtf((float)((a + 1) * b));
            h.x = g * cp; h.y = g * sp;
        } else if (ca == a - 1 && cb == b + 1) {
            float g = tt * sqrtf((float)(a * (b + 1)));
            h.x = -g * cp; h.y = g * sp;
        }
        float2 xs = make_float2(h.x * fs, h.y * fs);
        X[e] = xs;
        R[e] = make_float2(((r == c) ? 1.f : 0.f) + xs.x * 0.1f, xs.y * 0.1f);
    }
    __syncthreads();
    float2 acc[16];
    for (int j = 9; j >= 1; j--) {
        int q = 0;
        for (int e = t; e < 4096; e += 256, q++) {
            int r = e >> 6, c = e & 63;
            float2 a2 = make_float2(0.f, 0.f);
            for (int k = 0; k < 64; k++) cmac(a2, X[r * 64 + k], R[k * 64 + c]);
            acc[q] = a2;
        }
        __syncthreads();
        float inv = 1.f / (float)j;
        q = 0;
        for (int e = t; e < 4096; e += 256, q++) {
            int r = e >> 6, c = e & 63;
            R[e] = make_float2(((r == c) ? 1.f : 0.f) + acc[q].x * inv, acc[q].y * inv);
        }
        __syncthreads();
    }
    for (int sq = 0; sq < s; sq++) {
        int q = 0;
        for (int e = t; e < 4096; e += 256, q++) {
            int r = e >> 6, c = e & 63;
            float2 a2 = make_float2(0.f, 0.f);
            for (int k = 0; k < 64; k++) cmac(a2, R[r * 64 + k], R[k * 64 + c]);
            acc[q] = a2;
        }
        __syncthreads();
        q = 0;
        for (int e = t; e < 4096; e += 256, q++) R[e] = acc[q];
        __syncthreads();
    }
    for (int e = t; e < 512; e += 256) {
        int o = e >> 3, ka = e & 7;
        int n = (o >> 3) + (o & 7);
        int kb = n - ka;
        float2 v = make_float2(0.f, 0.f);
        if (kb >= 0 && kb <= 7) {
            int k = ka * 8 + kb;
            float ang = php * (float)(o & 7) + pre_i * (float)ka + pre_j * (float)kb;
            float sn, cs; __sincosf(ang, &sn, &cs);
            v = cmul(make_float2(cs, sn), R[o * 64 + k]);
        }
        bsG[blk * 512 + o * 8 + ka] = v;
    }
}

// ---------------------------------------------------------------------------
// Main simulation kernel. 1 block (256 thr)/sample, state in swizzled LDS.
// Gate tables flow: global -> (float4/thread prefetch regs) -> GB (4KB LDS)
// one gate ahead, inside the existing 2-barrier structure.
// ---------------------------------------------------------------------------

// Sparse two-mode gate, runtime wave index wq. Wave wq owns output rows
// a' = 2wq, 2wq+1 (16 outputs). G table in LDS (GB), layout
// [wq*128 + row*8 + ka], rows 0-7 -> (2wq,b), rows 8-15 -> (2wq+1,b),
// zero-padded for invalid (ka,kb). nxt: next gate's global table (nxtf4
// float4 elements = bytes/16) to prefetch into GB during the write phase.
template<int M1, int M2>
__device__ __forceinline__ void bs_gate(
    float2* S, float2* GB, const float2* __restrict__ nxt, int nxtf4,
    int t, int lane, int wq) {
    constexpr int st1 = 512 >> (3 * M1);
    constexpr int st2 = 512 >> (3 * M2);
    constexpr int freeA = (M1 != 0 && M2 != 0) ? 0 : ((M1 != 1 && M2 != 1) ? 1 : 2);
    constexpr int freeB = (M1 != 3 && M2 != 3) ? 3 : ((M1 != 2 && M2 != 2) ? 2 : 1);
    constexpr int sa = 512 >> (3 * freeA);
    constexpr int sb = 512 >> (3 * freeB);
    int fbase = (lane >> 3) * sa + (lane & 7) * sb;
    int pb = physw(fbase);
    const bool w1 = (wq & 1) != 0, w2 = (wq & 2) != 0;
    const float2* gw = GB + wq * 128;
    float4 pre;
    bool doPre = (nxt != nullptr) && (t < nxtf4);
    if (doPre) pre = ((const float4*)nxt)[t];
    float2 acc[16];
    #pragma unroll
    for (int j = 0; j < 16; j++) acc[j] = make_float2(0.f, 0.f);
    #pragma unroll
    for (int dn = 0; dn <= 8; dn++) {
        #pragma unroll
        for (int ka = 0; ka < 8; ka++) {
            if (ka > dn + 6 || dn - ka > 7) continue;   // invalid for every wq
            const int C0 = physw(ka * st1) ^ physw((((dn - ka + 0) & 7)) * st2);
            const int C1 = physw(ka * st1) ^ physw((((dn - ka + 2) & 7)) * st2);
            const int C2 = physw(ka * st1) ^ physw((((dn - ka + 4) & 7)) * st2);
            const int C3 = physw(ka * st1) ^ physw((((dn - ka + 6) & 7)) * st2);
            int pk = w2 ? (w1 ? C3 : C2) : (w1 ? C1 : C0);
            float2 sv = S[pb ^ pk];
            if (dn <= 7) cmac(acc[dn], gw[dn * 8 + ka], sv);
            if (dn >= 1) cmac(acc[8 + dn - 1], gw[(7 + dn) * 8 + ka], sv);
        }
    }
    __syncthreads();
    {
        const int W0 = physw(0 * st1), W1 = physw(2 * st1),
                  W2 = physw(4 * st1), W3 = physw(6 * st1);
        int pw = w2 ? (w1 ? W3 : W2) : (w1 ? W1 : W0);
        #pragma unroll
        for (int j = 0; j < 16; j++) {
            const int po = physw((j >> 3) * st1 + (j & 7) * st2);
            S[pb ^ pw ^ po] = acc[j];
        }
    }
    if (doPre) ((float4*)GB)[t] = pre;   // GB reads all done (barrier above)
    __syncthreads();
}

// Single-mode 8x8 dense gate; thread owns 2 private fibers. Table in GB
// (first 64 float2), transposed [k*8+i].
template<int MODE>
__device__ __forceinline__ void one_gate(
    float2* S, float2* GB, const float2* __restrict__ nxt, int nxtf4, int t) {
    constexpr int st = 512 >> (3 * MODE);
    constexpr int F0 = (MODE == 0) ? 64 : 512;
    constexpr int F1 = (MODE <= 1) ? 8 : 64;
    constexpr int F2 = (MODE == 3) ? 8 : 1;
    int f0 = t, f1 = t + 256;
    int fb0 = ((f0 >> 6) & 7) * F0 + ((f0 >> 3) & 7) * F1 + (f0 & 7) * F2;
    int fb1 = ((f1 >> 6) & 7) * F0 + ((f1 >> 3) & 7) * F1 + (f1 & 7) * F2;
    int pb0 = physw(fb0), pb1 = physw(fb1);
    float4 pre;
    bool doPre = (nxt != nullptr) && (t < nxtf4);
    if (doPre) pre = ((const float4*)nxt)[t];
    float2 a0[8], a1[8];
    #pragma unroll
    for (int i = 0; i < 8; i++) { a0[i] = make_float2(0.f, 0.f); a1[i] = make_float2(0.f, 0.f); }
    #pragma unroll
    for (int k = 0; k < 8; k++) {
        const int pk = physw(k * st);
        float2 s0 = S[pb0 ^ pk];
        float2 s1 = S[pb1 ^ pk];
        #pragma unroll
        for (int i = 0; i < 8; i++) {
            float2 g = GB[k * 8 + i];
            cmac(a0[i], g, s0); cmac(a1[i], g, s1);
        }
    }
    __syncthreads();   // separates GB reads from overwrite
    #pragma unroll
    for (int i = 0; i < 8; i++) {
        const int pi = physw(i * st);
        S[pb0 ^ pi] = a0[i];
        S[pb1 ^ pi] = a1[i];
    }
    if (doPre) ((float4*)GB)[t] = pre;
    __syncthreads();
}

__global__ __launch_bounds__(256, 4) void sim_kernel(
    const float* __restrict__ coh, const float2* __restrict__ sqm,
    const float2* __restrict__ dpm, const float2* __restrict__ bsG,
    float* __restrict__ out) {
    __shared__ float2 S[AMPS];
    __shared__ float2 GB[512];     // 4 KB single-buffer gate table
    __shared__ float ch[32];
    __shared__ float red[16];
    int b = blockIdx.x;
    int t = threadIdx.x;
    int lane = t & 63;
    int wq = __builtin_amdgcn_readfirstlane(t >> 6);

    if (t < 32) ch[t] = coh[b * 32 + t];
    ((float4*)GB)[t] = ((const float4*)bsG)[t];   // stage gate 0: 256 float4
    __syncthreads();
    for (int e = t; e < AMPS; e += 256) {
        float v = ch[e >> 9] * ch[8 + ((e >> 6) & 7)] * ch[16 + ((e >> 3) & 7)] * ch[24 + (e & 7)];
        S[physw(e)] = make_float2(v, 0.f);
    }
    __syncthreads();

    #pragma unroll 1
    for (int l = 0; l < NL; l++) {
        #pragma unroll 1
        for (int h = 0; h < 2; h++) {
            const float2* g = bsG + (size_t)(l * 12 + h * 6) * 512;
            const float2* u = ((h == 0) ? sqm : dpm) + (size_t)(l * 4) * 64;
            bool last = (l == NL - 1) && (h == 1);
            const float2* gn = (h == 0) ? (bsG + (size_t)(l * 12 + 6) * 512)
                                        : (bsG + (size_t)((l + 1) * 12) * 512);
            bs_gate<0, 1>(S, GB, g + 1 * 512, 256, t, lane, wq);
            bs_gate<0, 2>(S, GB, g + 2 * 512, 256, t, lane, wq);
            bs_gate<0, 3>(S, GB, g + 3 * 512, 256, t, lane, wq);
            bs_gate<1, 2>(S, GB, g + 4 * 512, 256, t, lane, wq);
            bs_gate<1, 3>(S, GB, g + 5 * 512, 256, t, lane, wq);
            bs_gate<2, 3>(S, GB, u + 0 * 64, 32, t, lane, wq);
            one_gate<0>(S, GB, u + 1 * 64, 32, t);
            one_gate<1>(S, GB, u + 2 * 64, 32, t);
            one_gate<2>(S, GB, u + 3 * 64, 32, t);
            one_gate<3>(S, GB, last ? nullptr : gn, last ? 0 : 256, t);
        }
    }

    // <n_w> per mode: iterate logical index, read physical slot.
    float ev0 = 0.f, ev1 = 0.f, ev2 = 0.f, ev3 = 0.f;
    for (int e = t; e < AMPS; e += 256) {
        float2 s = S[physw(e)];
        float pr = s.x * s.x + s.y * s.y;
        ev0 += pr * (float)(e >> 9);
        ev1 += pr * (float)((e >> 6) & 7);
        ev2 += pr * (float)((e >> 3) & 7);
        ev3 += pr * (float)(e & 7);
    }
    #pragma unroll
    for (int off = 32; off > 0; off >>= 1) {
        ev0 += __shfl_down(ev0, off);
        ev1 += __shfl_down(ev1, off);
        ev2 += __shfl_down(ev2, off);
        ev3 += __shfl_down(ev3, off);
    }
    __syncthreads();
    if (lane == 0) {
        red[wq * 4 + 0] = ev0;
        red[wq * 4 + 1] = ev1;
        red[wq * 4 + 2] = ev2;
        red[wq * 4 + 3] = ev3;
    }
    __syncthreads();
    if (t < 4) out[b * 4 + t] = red[t] + red[4 + t] + red[8 + t] + red[12 + t];
}

extern "C" void kernel_launch(void* const* d_in, const int* in_sizes, int n_in,
                              void* d_out, int out_size, void* d_ws, size_t ws_size,
                              hipStream_t stream) {
    const float* x    = (const float*)d_in[0];
    const float* th1  = (const float*)d_in[1];
    const float* ph1  = (const float*)d_in[2];
    const float* th2  = (const float*)d_in[3];
    const float* ph2  = (const float*)d_in[4];
    const float* dpr  = (const float*)d_in[5];
    const float* dpph = (const float*)d_in[6];
    const float* sqr  = (const float*)d_in[7];
    const float* sqph = (const float*)d_in[8];
    const float* kerr = (const float*)d_in[9];
    float* out = (float*)d_out;

    int Bn = in_sizes[0] / NM;

    char* ws = (char*)d_ws;
    float*  coh = (float*)ws;                          // Bn*32 floats
    size_t coh_bytes = (size_t)Bn * 32 * sizeof(float);
    float2* sqm = (float2*)(ws + coh_bytes);           // 16*64 float2
    float2* dpm = (float2*)(ws + coh_bytes + 16 * 64 * sizeof(float2));
    float2* bsG = (float2*)(ws + coh_bytes + 32 * 64 * sizeof(float2)); // 48*512 float2

    int total = Bn * NM;
    coh_kernel<<<(total + 255) / 256, 256, 0, stream>>>(x, coh, total);
    expm8_kernel<<<32, 64, 0, stream>>>(sqr, sqph, dpr, dpph, kerr, sqm, dpm);
    expm64_kernel<<<48, 256, 0, stream>>>(th1, ph1, th2, ph2, bsG);
    sim_kernel<<<Bn, 256, 0, stream>>>(coh, sqm, dpm, bsG, out);
}

// Round 8
// 7702.167 us; speedup vs baseline: 1.3502x; 1.3502x over previous
//
#include <hip/hip_runtime.h>

// CV quantum neural network simulator, D=8 cutoff, M=4 modes, L=4 layers.
// R8: __launch_bounds__(256) WITHOUT min-waves hint. R2..R7 all had
// (256,4) which capped the allocator at 64 VGPRs -> every structure spilled
// acc[16] to scratch (R7: 17GB HBM scratch traffic, VALUBusy 7%). R1 (no
// hint) got 156 VGPRs and zero spill. LDS 37.5KB still gives 4 blocks/CU.
// Also: G values paired into float4 broadcasts (one ds_read_b128 per
// (dn,ka) term instead of two b64) - BS table re-laid out as
// [wq][dn][ka] -> float4{row_a gate val, row_b gate val}.

#define NM 4
#define NL 4
#define AMPS 4096

__device__ __forceinline__ void cmac(float2& acc, float2 a, float2 b) {
    acc.x = fmaf(a.x, b.x, acc.x);
    acc.x = fmaf(-a.y, b.y, acc.x);
    acc.y = fmaf(a.x, b.y, acc.y);
    acc.y = fmaf(a.y, b.x, acc.y);
}
__device__ __forceinline__ float2 cmul(float2 a, float2 b) {
    return make_float2(a.x * b.x - a.y * b.y, a.x * b.y + a.y * b.x);
}

// F2-linear physical-slot map (bank-conflict-free for all access patterns).
// XOR-linear: physw(a^b) = physw(a)^physw(b).
__device__ __host__ __forceinline__ constexpr int physw(int e) {
    int l0 = ((e >> 0) ^ (e >> 5) ^ (e >> 7) ^ (e >> 9)) & 1;
    int l1 = ((e >> 1) ^ (e >> 3) ^ (e >> 8) ^ (e >> 10)) & 1;
    int l2 = ((e >> 2) ^ (e >> 4) ^ (e >> 6) ^ (e >> 11)) & 1;
    int l3 = ((e >> 3) ^ (e >> 6) ^ (e >> 9)) & 1;
    return (e & ~15) | l0 | (l1 << 1) | (l2 << 2) | (l3 << 3);
}

// ---------------------------------------------------------------------------
// Kernel 1: coherent vectors = first column of expm(x*(AD - A)).
// ---------------------------------------------------------------------------
__global__ void coh_kernel(const float* __restrict__ x, float* __restrict__ coh, int total) {
    int t = blockIdx.x * blockDim.x + threadIdx.x;
    if (t >= total) return;
    float alpha = x[t];
    const float sq1 = 1.0f, sq2 = 1.41421356f, sq3 = 1.73205081f, sq4 = 2.0f,
                sq5 = 2.23606798f, sq6 = 2.44948975f, sq7 = 2.64575131f;
    float v0 = 1.f, v1 = 0.f, v2 = 0.f, v3 = 0.f, v4 = 0.f, v5 = 0.f, v6 = 0.f, v7 = 0.f;
    const int NS = 32;
    float h = alpha / (float)NS;
    for (int s = 0; s < NS; s++) {
        float w0 = v0, w1 = v1, w2 = v2, w3 = v3, w4 = v4, w5 = v5, w6 = v6, w7 = v7;
        float t0 = v0, t1 = v1, t2 = v2, t3 = v3, t4 = v4, t5 = v5, t6 = v6, t7 = v7;
        #pragma unroll
        for (int j = 1; j <= 8; j++) {
            float c = h / (float)j;
            float n0 = c * (          - sq1 * t1);
            float n1 = c * (sq1 * t0 - sq2 * t2);
            float n2 = c * (sq2 * t1 - sq3 * t3);
            float n3 = c * (sq3 * t2 - sq4 * t4);
            float n4 = c * (sq4 * t3 - sq5 * t5);
            float n5 = c * (sq5 * t4 - sq6 * t6);
            float n6 = c * (sq6 * t5 - sq7 * t7);
            float n7 = c * (sq7 * t6            );
            t0 = n0; t1 = n1; t2 = n2; t3 = n3; t4 = n4; t5 = n5; t6 = n6; t7 = n7;
            w0 += t0; w1 += t1; w2 += t2; w3 += t3; w4 += t4; w5 += t5; w6 += t6; w7 += t7;
        }
        v0 = w0; v1 = w1; v2 = w2; v3 = w3; v4 = w4; v5 = w5; v6 = w6; v7 = w7;
    }
    float* dst = coh + t * 8;
    dst[0] = v0; dst[1] = v1; dst[2] = v2; dst[3] = v3;
    dst[4] = v4; dst[5] = v5; dst[6] = v6; dst[7] = v7;
}

// ---------------------------------------------------------------------------
// Kernel 2: 8x8 complex expm. Blocks 0..15: squeeze. Blocks 16..31:
// displacement with Kerr folded (row scale). Stored transposed [k*8+i].
// ---------------------------------------------------------------------------
__global__ __launch_bounds__(64) void expm8_kernel(
    const float* __restrict__ sqr, const float* __restrict__ sqph,
    const float* __restrict__ dpr, const float* __restrict__ dpph,
    const float* __restrict__ kerr,
    float2* __restrict__ sqm, float2* __restrict__ dpm) {
    __shared__ float2 X[64], R[64];
    int t = threadIdx.x;
    int r = t >> 3, c = t & 7;
    int bid = blockIdx.x;
    float2 h = make_float2(0.f, 0.f);
    float normb;
    if (bid < 16) {
        float rr = sqr[bid], ph = sqph[bid];
        float zr = rr * cosf(ph), zi = rr * sinf(ph);
        if (c == r + 2) { float f = 0.5f * sqrtf((float)((r + 1) * (r + 2))); h.x =  f * zr; h.y = -f * zi; }
        if (r == c + 2) { float f = 0.5f * sqrtf((float)((c + 1) * (c + 2))); h.x = -f * zr; h.y = -f * zi; }
        normb = fabsf(rr) * 5.5f;
    } else {
        int g = bid - 16;
        float rr = dpr[g], ph = dpph[g];
        float am = rr * cosf(ph);
        float aph = rr * sinf(ph);
        float ar = am * cosf(aph), ai = am * sinf(aph);
        if (r == c + 1) { float f = sqrtf((float)r); h.x += ar * f; h.y += ai * f; }
        if (c == r + 1) { float f = sqrtf((float)c); h.x -= ar * f; h.y += ai * f; }
        normb = fabsf(am) * 5.5f;
    }
    int s = 0;
    while (normb > 0.2f && s < 20) { normb *= 0.5f; s++; }
    float fs = 1.f;
    for (int q = 0; q < s; q++) fs *= 0.5f;
    float2 xs = make_float2(h.x * fs, h.y * fs);
    X[t] = xs;
    float idel = (r == c) ? 1.f : 0.f;
    R[t] = make_float2(idel + xs.x / 9.f, xs.y / 9.f);
    __syncthreads();
    for (int j = 8; j >= 1; j--) {
        float2 acc = make_float2(0.f, 0.f);
        #pragma unroll
        for (int k = 0; k < 8; k++) cmac(acc, X[r * 8 + k], R[k * 8 + c]);
        __syncthreads();
        float inv = 1.f / (float)j;
        R[t] = make_float2(idel + acc.x * inv, acc.y * inv);
        __syncthreads();
    }
    for (int q = 0; q < s; q++) {
        float2 acc = make_float2(0.f, 0.f);
        #pragma unroll
        for (int k = 0; k < 8; k++) cmac(acc, R[r * 8 + k], R[k * 8 + c]);
        __syncthreads();
        R[t] = acc;
        __syncthreads();
    }
    float2 v = R[t];
    if (bid >= 16) {
        float kp = kerr[bid - 16];
        float ang = kp * (float)(r * r);
        float sn, cs; __sincosf(ang, &sn, &cs);
        v = cmul(make_float2(cs, sn), v);
        dpm[(bid - 16) * 64 + c * 8 + r] = v;
    } else {
        sqm[bid * 64 + c * 8 + r] = v;
    }
}

// ---------------------------------------------------------------------------
// Kernel 3: 64x64 complex expm for 48 beamsplitters, diag rotations folded.
// Output layout (R8, paired): bsP[blk*288 + wq*72 + dn*8 + ka] = float4{
//   U'[2wq*8 + dn][ka*8+kb]          (or 0 if dn>7 or kb out of [0,7]),
//   U'[(2wq+1)*8 + dn-1][ka*8+kb]    (or 0 if dn<1 or kb out of [0,7]) }
// with kb = 2wq + dn - ka.
// ---------------------------------------------------------------------------
__global__ __launch_bounds__(256) void expm64_kernel(
    const float* __restrict__ th1, const float* __restrict__ ph1,
    const float* __restrict__ th2, const float* __restrict__ ph2,
    float4* __restrict__ bsP) {
    __shared__ float2 X[4096], R[4096];
    int blk = blockIdx.x;
    int l = blk / 12, idx = blk % 12;
    int p = (idx < 6) ? idx : idx - 6;
    int mi = (p < 3) ? 0 : ((p < 5) ? 1 : 2);
    int mj = (p == 0) ? 1 : ((p == 1 || p == 3) ? 2 : 3);
    const float* th = (idx < 6) ? th1 : th2;
    const float* ph = (idx < 6) ? ph1 : ph2;
    float tt = th[l * 16 + mi * 4 + mj];
    float pp = ph[l * 16 + mi * 4 + mj];
    float cp = cosf(pp), sp = sinf(pp);
    float php = ph[l * 16 + mj * 4 + mi];
    float pre_i = 0.f, pre_j = 0.f;
    if (p == 0) { pre_i = ph[l * 16 + 0]; pre_j = ph[l * 16 + 5]; }
    else if (p == 1) { pre_j = ph[l * 16 + 10]; }
    else if (p == 2) { pre_j = ph[l * 16 + 15]; }
    int t = threadIdx.x;
    float normb = fabsf(tt) * 13.94f;
    int s = 0;
    while (normb > 0.2f && s < 20) { normb *= 0.5f; s++; }
    float fs = 1.f;
    for (int q = 0; q < s; q++) fs *= 0.5f;
    for (int e = t; e < 4096; e += 256) {
        int r = e >> 6, c = e & 63;
        int a = r >> 3, b = r & 7, ca = c >> 3, cb = c & 7;
        float2 h = make_float2(0.f, 0.f);
        if (ca == a + 1 && cb == b - 1) {
            float g = tt * sqrtf((float)((a + 1) * b));
            h.x = g * cp; h.y = g * sp;
        } else if (ca == a - 1 && cb == b + 1) {
            float g = tt * sqrtf((float)(a * (b + 1)));
            h.x = -g * cp; h.y = g * sp;
        }
        float2 xs = make_float2(h.x * fs, h.y * fs);
        X[e] = xs;
        R[e] = make_float2(((r == c) ? 1.f : 0.f) + xs.x * 0.1f, xs.y * 0.1f);
    }
    __syncthreads();
    float2 acc[16];
    for (int j = 9; j >= 1; j--) {
        int q = 0;
        for (int e = t; e < 4096; e += 256, q++) {
            int r = e >> 6, c = e & 63;
            float2 a2 = make_float2(0.f, 0.f);
            for (int k = 0; k < 64; k++) cmac(a2, X[r * 64 + k], R[k * 64 + c]);
            acc[q] = a2;
        }
        __syncthreads();
        float inv = 1.f / (float)j;
        q = 0;
        for (int e = t; e < 4096; e += 256, q++) {
            int r = e >> 6, c = e & 63;
            R[e] = make_float2(((r == c) ? 1.f : 0.f) + acc[q].x * inv, acc[q].y * inv);
        }
        __syncthreads();
    }
    for (int sq = 0; sq < s; sq++) {
        int q = 0;
        for (int e = t; e < 4096; e += 256, q++) {
            int r = e >> 6, c = e & 63;
            float2 a2 = make_float2(0.f, 0.f);
            for (int k = 0; k < 64; k++) cmac(a2, R[r * 64 + k], R[k * 64 + c]);
            acc[q] = a2;
        }
        __syncthreads();
        q = 0;
        for (int e = t; e < 4096; e += 256, q++) R[e] = acc[q];
        __syncthreads();
    }
    for (int e = t; e < 288; e += 256) {
        int wq = e / 72, rem = e % 72;
        int dn = rem >> 3, ka = rem & 7;
        int n = 2 * wq + dn;
        int kb = n - ka;
        float2 v1 = make_float2(0.f, 0.f), v2 = make_float2(0.f, 0.f);
        if (kb >= 0 && kb <= 7) {
            int k = ka * 8 + kb;
            float colang = pre_i * (float)ka + pre_j * (float)kb;
            if (dn <= 7) {
                int o = 2 * wq * 8 + dn;
                float ang = php * (float)dn + colang;
                float sn, cs; __sincosf(ang, &sn, &cs);
                v1 = cmul(make_float2(cs, sn), R[o * 64 + k]);
            }
            if (dn >= 1) {
                int o = (2 * wq + 1) * 8 + (dn - 1);
                float ang = php * (float)(dn - 1) + colang;
                float sn, cs; __sincosf(ang, &sn, &cs);
                v2 = cmul(make_float2(cs, sn), R[o * 64 + k]);
            }
        }
        bsP[blk * 288 + e] = make_float4(v1.x, v1.y, v2.x, v2.y);
    }
}

// ---------------------------------------------------------------------------
// Main simulation kernel. 1 block (256 thr)/sample, state in swizzled LDS.
// Gate tables: global -> up-to-2 float4/thread prefetch regs -> GB4 LDS
// buffer (stored in write phase behind the mid-barrier).
// ---------------------------------------------------------------------------

// Sparse two-mode gate, runtime wave index wq. Wave wq owns output rows
// a' = 2wq, 2wq+1 (16 outputs). Paired G table in GB4: [wq*72 + dn*8 + ka]
// = float4{g_row_a, g_row_b}, zero-padded for invalid (ka,kb).
template<int M1, int M2>
__device__ __forceinline__ void bs_gate(
    float2* S, float4* GB4, const float4* __restrict__ nxt, int nxtf4,
    int t, int lane, int wq) {
    constexpr int st1 = 512 >> (3 * M1);
    constexpr int st2 = 512 >> (3 * M2);
    constexpr int freeA = (M1 != 0 && M2 != 0) ? 0 : ((M1 != 1 && M2 != 1) ? 1 : 2);
    constexpr int freeB = (M1 != 3 && M2 != 3) ? 3 : ((M1 != 2 && M2 != 2) ? 2 : 1);
    constexpr int sa = 512 >> (3 * freeA);
    constexpr int sb = 512 >> (3 * freeB);
    int fbase = (lane >> 3) * sa + (lane & 7) * sb;
    int pb = physw(fbase);
    const bool w1 = (wq & 1) != 0, w2 = (wq & 2) != 0;
    const float4* gw = GB4 + wq * 72;
    float4 preA, preB;
    bool dA = (nxt != nullptr) && (t < nxtf4);
    bool dB = (nxt != nullptr) && (t + 256 < nxtf4);
    if (dA) preA = nxt[t];
    if (dB) preB = nxt[t + 256];
    float2 acc[16];
    #pragma unroll
    for (int j = 0; j < 16; j++) acc[j] = make_float2(0.f, 0.f);
    #pragma unroll
    for (int dn = 0; dn <= 8; dn++) {
        #pragma unroll
        for (int ka = 0; ka < 8; ka++) {
            if (ka > dn + 6 || dn - ka > 7) continue;   // invalid for every wq
            const int C0 = physw(ka * st1) ^ physw((((dn - ka + 0) & 7)) * st2);
            const int C1 = physw(ka * st1) ^ physw((((dn - ka + 2) & 7)) * st2);
            const int C2 = physw(ka * st1) ^ physw((((dn - ka + 4) & 7)) * st2);
            const int C3 = physw(ka * st1) ^ physw((((dn - ka + 6) & 7)) * st2);
            int pk = w2 ? (w1 ? C3 : C2) : (w1 ? C1 : C0);
            float2 sv = S[pb ^ pk];
            float4 g = gw[dn * 8 + ka];
            if (dn <= 7) cmac(acc[dn], make_float2(g.x, g.y), sv);
            if (dn >= 1) cmac(acc[8 + dn - 1], make_float2(g.z, g.w), sv);
        }
    }
    __syncthreads();
    {
        const int W0 = physw(0 * st1), W1 = physw(2 * st1),
                  W2 = physw(4 * st1), W3 = physw(6 * st1);
        int pw = w2 ? (w1 ? W3 : W2) : (w1 ? W1 : W0);
        #pragma unroll
        for (int j = 0; j < 16; j++) {
            const int po = physw((j >> 3) * st1 + (j & 7) * st2);
            S[pb ^ pw ^ po] = acc[j];
        }
    }
    if (dA) GB4[t] = preA;            // GB4 reads all done (barrier above)
    if (dB) GB4[t + 256] = preB;
    __syncthreads();
}

// Single-mode 8x8 dense gate; thread owns 2 private fibers. Table in GB4
// (first 32 float4 = 64 float2, transposed [k*8+i]).
template<int MODE>
__device__ __forceinline__ void one_gate(
    float2* S, float4* GB4, const float4* __restrict__ nxt, int nxtf4, int t) {
    constexpr int st = 512 >> (3 * MODE);
    constexpr int F0 = (MODE == 0) ? 64 : 512;
    constexpr int F1 = (MODE <= 1) ? 8 : 64;
    constexpr int F2 = (MODE == 3) ? 8 : 1;
    int f0 = t, f1 = t + 256;
    int fb0 = ((f0 >> 6) & 7) * F0 + ((f0 >> 3) & 7) * F1 + (f0 & 7) * F2;
    int fb1 = ((f1 >> 6) & 7) * F0 + ((f1 >> 3) & 7) * F1 + (f1 & 7) * F2;
    int pb0 = physw(fb0), pb1 = physw(fb1);
    float4 preA, preB;
    bool dA = (nxt != nullptr) && (t < nxtf4);
    bool dB = (nxt != nullptr) && (t + 256 < nxtf4);
    if (dA) preA = nxt[t];
    if (dB) preB = nxt[t + 256];
    float2 a0[8], a1[8];
    #pragma unroll
    for (int i = 0; i < 8; i++) { a0[i] = make_float2(0.f, 0.f); a1[i] = make_float2(0.f, 0.f); }
    #pragma unroll
    for (int k = 0; k < 8; k++) {
        const int pk = physw(k * st);
        float2 s0 = S[pb0 ^ pk];
        float2 s1 = S[pb1 ^ pk];
        #pragma unroll
        for (int i2 = 0; i2 < 4; i2++) {
            float4 gp = GB4[k * 4 + i2];
            float2 ga = make_float2(gp.x, gp.y), gb = make_float2(gp.z, gp.w);
            cmac(a0[2 * i2], ga, s0); cmac(a1[2 * i2], ga, s1);
            cmac(a0[2 * i2 + 1], gb, s0); cmac(a1[2 * i2 + 1], gb, s1);
        }
    }
    __syncthreads();   // separates GB4/S reads from overwrite
    #pragma unroll
    for (int i = 0; i < 8; i++) {
        const int pi = physw(i * st);
        S[pb0 ^ pi] = a0[i];
        S[pb1 ^ pi] = a1[i];
    }
    if (dA) GB4[t] = preA;
    if (dB) GB4[t + 256] = preB;
    __syncthreads();
}

__global__ __launch_bounds__(256) void sim_kernel(
    const float* __restrict__ coh, const float4* __restrict__ sqm,
    const float4* __restrict__ dpm, const float4* __restrict__ bsP,
    float* __restrict__ out) {
    __shared__ float2 S[AMPS];
    __shared__ float4 GB4[288];    // 4.5 KB gate-table buffer
    __shared__ float ch[32];
    __shared__ float red[16];
    int b = blockIdx.x;
    int t = threadIdx.x;
    int lane = t & 63;
    int wq = __builtin_amdgcn_readfirstlane(t >> 6);

    if (t < 32) ch[t] = coh[b * 32 + t];
    GB4[t] = bsP[t];                         // stage gate 0 (288 float4)
    if (t < 32) GB4[t + 256] = bsP[t + 256];
    __syncthreads();
    for (int e = t; e < AMPS; e += 256) {
        float v = ch[e >> 9] * ch[8 + ((e >> 6) & 7)] * ch[16 + ((e >> 3) & 7)] * ch[24 + (e & 7)];
        S[physw(e)] = make_float2(v, 0.f);
    }
    __syncthreads();

    #pragma unroll 1
    for (int l = 0; l < NL; l++) {
        #pragma unroll 1
        for (int h = 0; h < 2; h++) {
            const float4* g = bsP + (size_t)(l * 12 + h * 6) * 288;
            const float4* u = ((h == 0) ? sqm : dpm) + (size_t)(l * 4) * 32;
            bool last = (l == NL - 1) && (h == 1);
            const float4* gn = (h == 0) ? (bsP + (size_t)(l * 12 + 6) * 288)
                                        : (bsP + (size_t)((l + 1) * 12) * 288);
            bs_gate<0, 1>(S, GB4, g + 1 * 288, 288, t, lane, wq);
            bs_gate<0, 2>(S, GB4, g + 2 * 288, 288, t, lane, wq);
            bs_gate<0, 3>(S, GB4, g + 3 * 288, 288, t, lane, wq);
            bs_gate<1, 2>(S, GB4, g + 4 * 288, 288, t, lane, wq);
            bs_gate<1, 3>(S, GB4, g + 5 * 288, 288, t, lane, wq);
            bs_gate<2, 3>(S, GB4, u + 0 * 32, 32, t, lane, wq);
            one_gate<0>(S, GB4, u + 1 * 32, 32, t);
            one_gate<1>(S, GB4, u + 2 * 32, 32, t);
            one_gate<2>(S, GB4, u + 3 * 32, 32, t);
            one_gate<3>(S, GB4, last ? nullptr : gn, last ? 0 : 288, t);
        }
    }

    // <n_w> per mode: iterate logical index, read physical slot.
    float ev0 = 0.f, ev1 = 0.f, ev2 = 0.f, ev3 = 0.f;
    for (int e = t; e < AMPS; e += 256) {
        float2 s = S[physw(e)];
        float pr = s.x * s.x + s.y * s.y;
        ev0 += pr * (float)(e >> 9);
        ev1 += pr * (float)((e >> 6) & 7);
        ev2 += pr * (float)((e >> 3) & 7);
        ev3 += pr * (float)(e & 7);
    }
    #pragma unroll
    for (int off = 32; off > 0; off >>= 1) {
        ev0 += __shfl_down(ev0, off);
        ev1 += __shfl_down(ev1, off);
        ev2 += __shfl_down(ev2, off);
        ev3 += __shfl_down(ev3, off);
    }
    __syncthreads();
    if (lane == 0) {
        red[wq * 4 + 0] = ev0;
        red[wq * 4 + 1] = ev1;
        red[wq * 4 + 2] = ev2;
        red[wq * 4 + 3] = ev3;
    }
    __syncthreads();
    if (t < 4) out[b * 4 + t] = red[t] + red[4 + t] + red[8 + t] + red[12 + t];
}

extern "C" void kernel_launch(void* const* d_in, const int* in_sizes, int n_in,
                              void* d_out, int out_size, void* d_ws, size_t ws_size,
                              hipStream_t stream) {
    const float* x    = (const float*)d_in[0];
    const float* th1  = (const float*)d_in[1];
    const float* ph1  = (const float*)d_in[2];
    const float* th2  = (const float*)d_in[3];
    const float* ph2  = (const float*)d_in[4];
    const float* dpr  = (const float*)d_in[5];
    const float* dpph = (const float*)d_in[6];
    const float* sqr  = (const float*)d_in[7];
    const float* sqph = (const float*)d_in[8];
    const float* kerr = (const float*)d_in[9];
    float* out = (float*)d_out;

    int Bn = in_sizes[0] / NM;

    char* ws = (char*)d_ws;
    float*  coh = (float*)ws;                          // Bn*32 floats
    size_t coh_bytes = (size_t)Bn * 32 * sizeof(float);
    float2* sqm = (float2*)(ws + coh_bytes);           // 16*64 float2
    float2* dpm = (float2*)(ws + coh_bytes + 16 * 64 * sizeof(float2));
    float4* bsP = (float4*)(ws + coh_bytes + 32 * 64 * sizeof(float2)); // 48*288 float4

    int total = Bn * NM;
    coh_kernel<<<(total + 255) / 256, 256, 0, stream>>>(x, coh, total);
    expm8_kernel<<<32, 64, 0, stream>>>(sqr, sqph, dpr, dpph, kerr, sqm, dpm);
    expm64_kernel<<<48, 256, 0, stream>>>(th1, ph1, th2, ph2, bsP);
    sim_kernel<<<Bn, 256, 0, stream>>>(coh, (const float4*)sqm, (const float4*)dpm, bsP, out);
}